// Round 10
// baseline (199.699 us; speedup 1.0000x reference)
//
#include <hip/hip_runtime.h>

typedef __bf16 bf16x8 __attribute__((ext_vector_type(8)));
typedef float  f32x4  __attribute__((ext_vector_type(4)));
typedef float  f32x16 __attribute__((ext_vector_type(16)));
typedef unsigned int uint32x4 __attribute__((ext_vector_type(4)));

#define MFMA16(a, b, c) __builtin_amdgcn_mfma_f32_16x16x32_bf16((a), (b), (c), 0, 0, 0)
#define MFMA32(a, b, c) __builtin_amdgcn_mfma_f32_32x32x16_bf16((a), (b), (c), 0, 0, 0)

// no builtin for cvt_pk on gfx950 (learn_hip m240) -> inline asm
#define CVTPK(d, x, y) asm("v_cvt_pk_bf16_f32 %0, %1, %2" : "=v"(d) : "v"(x), "v"(y))
// v_permlane32_swap: dst.hi <-> src.lo (CDNA4). Both outputs used.
#define PLSWAP(a, b)   asm("v_permlane32_swap_b32 %0, %1" : "+v"(a), "+v"(b))

// raw barrier: drain own ds ops (lgkm) for cross-wave visibility, but keep
// global prefetch loads IN FLIGHT across the barrier (no vmcnt drain).
#define BAR_KEEP_VMEM() asm volatile("s_waitcnt lgkmcnt(0)\n\ts_barrier" ::: "memory")

__device__ inline float fast_exp2(float x) {
#if __has_builtin(__builtin_amdgcn_exp2f)
    return __builtin_amdgcn_exp2f(x);   // single v_exp_f32
#else
    return exp2f(x);
#endif
}

constexpr int SEQ = 2048;
constexpr int DM  = 1024;
constexpr int NH  = 16;
constexpr int HD  = 64;
constexpr int BATCH = 2;

// load 8 consecutive f32, convert to bf16x8 (RNE)
__device__ inline bf16x8 ld8_f32(const float* p) {
    f32x4 a = *(const f32x4*)p;
    f32x4 b = *(const f32x4*)(p + 4);
    bf16x8 r;
    r[0] = (__bf16)a[0]; r[1] = (__bf16)a[1]; r[2] = (__bf16)a[2]; r[3] = (__bf16)a[3];
    r[4] = (__bf16)b[0]; r[5] = (__bf16)b[1]; r[6] = (__bf16)b[2]; r[7] = (__bf16)b[3];
    return r;
}

// ---------------------------------------------------------------------------
// Kernel 1: per-head projections (unchanged). Q pre-scaled by 1/8*log2(e).
// ---------------------------------------------------------------------------
__global__ __launch_bounds__(256)
void proj_kernel(const float* __restrict__ Xq, const float* __restrict__ Xk,
                 const float* __restrict__ Xv,
                 const float* __restrict__ Wq, const float* __restrict__ Wk,
                 const float* __restrict__ Wv,
                 __bf16* __restrict__ Qp, __bf16* __restrict__ Kp,
                 __bf16* __restrict__ Vp)
{
    const int tid  = threadIdx.x;
    const int w    = tid >> 6;
    const int lane = tid & 63;
    const int quad = lane >> 4;
    const int l16  = lane & 15;
    const int sblk = blockIdx.x;
    const int bh   = blockIdx.y;
    const int tz   = blockIdx.z;

    const float* X = (tz == 0) ? Xq : (tz == 1) ? Xk : Xv;
    const float* W = (tz == 0) ? Wq : (tz == 1) ? Wk : Wv;
    __bf16*      O = (tz == 0) ? Qp : (tz == 1) ? Kp : Vp;
    const float scale = (tz == 0) ? (0.125f * 1.44269504088896f) : 1.0f;

    const int b = bh >> 4, h = bh & 15;
    const int mrow = sblk * 64 + w * 16 + l16;

    const size_t xoff = (size_t)(b * SEQ + mrow) * DM + h * HD + quad * 8;
    bf16x8 a0 = ld8_f32(X + xoff);
    bf16x8 a1 = ld8_f32(X + xoff + 32);

    f32x4 acc[4];
    #pragma unroll
    for (int nt = 0; nt < 4; ++nt) {
        const size_t woff = (size_t)(nt * 16 + l16) * HD + quad * 8;
        bf16x8 b0 = ld8_f32(W + woff);
        bf16x8 b1 = ld8_f32(W + woff + 32);
        f32x4 c = {0.f, 0.f, 0.f, 0.f};
        c = MFMA16(a0, b0, c);
        c = MFMA16(a1, b1, c);
        acc[nt] = c;
    }

    __bf16* obase = O + (size_t)bh * SEQ * HD;
    #pragma unroll
    for (int nt = 0; nt < 4; ++nt) {
        #pragma unroll
        for (int r = 0; r < 4; ++r) {
            const int srow = sblk * 64 + w * 16 + quad * 4 + r;
            obase[(size_t)srow * HD + nt * 16 + l16] = (__bf16)(acc[nt][r] * scale);
        }
    }
}

// ---------------------------------------------------------------------------
// Kernel 2: causal flash attention. Round 10: K LDS staging DELETED (guide
// common-mistake #7 / m169: don't LDS-stage L2-resident data). K fragments
// are loaded straight from global (L2-hit) into registers, depth-2 ahead,
// issued right after their previous consumption. Barrier now guards only V
// (which keeps LDS for the transpose pack). Post-barrier QK^T starts with
// zero lgkm wait. Paired 512-block grid, XCD-pinned bh, setprio — unchanged.
// Epilogue scratch relocated to the (dead) VT2 region.
// ---------------------------------------------------------------------------
__global__ __launch_bounds__(256, 2)
void attn_kernel(const __bf16* __restrict__ Qp, const __bf16* __restrict__ Kp,
                 const __bf16* __restrict__ Vp, __bf16* __restrict__ AO)
{
    __shared__ __align__(16) unsigned int VT2[2][64 * 36];  // V^T packed + epi scratch

    const int tid  = threadIdx.x;
    const int w    = tid >> 6;
    const int lane = tid & 63;
    const int hi   = lane >> 5;
    const int l32  = lane & 31;
    const int qg   = w >> 1;        // q sub-tile (32 rows)
    const int kg   = w & 1;         // k half of the 64-chunk

    // XCD swizzle (round 3): xcd = L%8, pr fastest within xcd, bh pinned.
    const int L   = blockIdx.x;
    const int pr  = (L >> 3) & 15;              // pair index 0..15
    const int bh  = (L & 7) + 8 * (L >> 7);     // 0..31

    const __bf16* Qb = Qp + (size_t)bh * SEQ * HD;
    const __bf16* Kb = Kp + (size_t)bh * SEQ * HD;
    const __bf16* Vb = Vp + (size_t)bh * SEQ * HD;

    const int jp = tid & 31, d0 = (tid >> 5) * 8;

    // per-lane K fragment base: row = 32*kg + l32, col = hi*8 (+ i*16)
    const __bf16* Kfrag = Kb + (size_t)(32 * kg + l32) * HD + hi * 8;

    #pragma unroll
    for (int phase = 0; phase < 2; ++phase) {
        const int tile = (phase == 0) ? (31 - pr) : pr;  // heavy first
        const int q0   = tile * 64;
        const int nkc  = tile + 1;

        __syncthreads();  // phase boundary: epilogue scratch reads done

        // Q B-frags in registers: B[n=q=l32][k = i*16 + hi*8 + j]
        const __bf16* qp = Qb + (size_t)(q0 + 32 * qg + l32) * HD + hi * 8;
        const bf16x8 qb0 = *(const bf16x8*)(qp);
        const bf16x8 qb1 = *(const bf16x8*)(qp + 16);
        const bf16x8 qb2 = *(const bf16x8*)(qp + 32);
        const bf16x8 qb3 = *(const bf16x8*)(qp + 48);

        f32x16 accO[2];
        #pragma unroll
        for (int et = 0; et < 2; ++et) {
            #pragma unroll
            for (int r = 0; r < 16; ++r) accO[et][r] = 0.f;
        }
        float rs0 = 0.f, rs1 = 0.f;

        // prologue: K frags chunk0 -> set A, chunk1 -> set B; V likewise.
        bf16x8 kA0, kA1, kA2, kA3, kB0, kB1, kB2, kB3;
        uint32x4 vAl, vAh, vBl, vBh;
        kA0 = *(const bf16x8*)(Kfrag);
        kA1 = *(const bf16x8*)(Kfrag + 16);
        kA2 = *(const bf16x8*)(Kfrag + 32);
        kA3 = *(const bf16x8*)(Kfrag + 48);
        vAl = *(const uint32x4*)(Vb + (size_t)(2 * jp) * HD + d0);
        vAh = *(const uint32x4*)(Vb + (size_t)(2 * jp + 1) * HD + d0);
        if (nkc > 1) {
            const __bf16* kf1 = Kfrag + (size_t)64 * HD;
            kB0 = *(const bf16x8*)(kf1);
            kB1 = *(const bf16x8*)(kf1 + 16);
            kB2 = *(const bf16x8*)(kf1 + 32);
            kB3 = *(const bf16x8*)(kf1 + 48);
            vBl = *(const uint32x4*)(Vb + (size_t)(64 + 2 * jp) * HD + d0);
            vBh = *(const uint32x4*)(Vb + (size_t)(64 + 2 * jp + 1) * HD + d0);
        }

        auto STEP = [&](int kc, int buf, bf16x8& k0, bf16x8& k1, bf16x8& k2,
                        bf16x8& k3, uint32x4& vl, uint32x4& vh) {
            // ---- stage V into LDS buf (transpose pair-pack) ----
            #pragma unroll
            for (int i2 = 0; i2 < 4; ++i2) {
                const unsigned int va = vl[i2], vb = vh[i2];
                VT2[buf][(d0 + 2 * i2    ) * 36 + jp] = (va & 0xffffu) | (vb << 16);
                VT2[buf][(d0 + 2 * i2 + 1) * 36 + jp] = (va >> 16) | (vb & 0xffff0000u);
            }
            // ---- issue V loads for chunk kc+2 BEFORE the barrier ----
            if (kc + 2 < nkc) {
                const size_t o = (size_t)(kc + 2) * 64;
                vl = *(const uint32x4*)(Vb + (o + 2 * jp) * HD + d0);
                vh = *(const uint32x4*)(Vb + (o + 2 * jp + 1) * HD + d0);
            }
            BAR_KEEP_VMEM();   // V writes visible; all global loads stay in flight

            // wave (qg=0,kg=1) at diagonal chunk: fully masked -> skip compute
            if (!(kc == tile && qg == 0 && kg == 1)) {
                // ---- S^T = K.Q^T — K frags already in registers, no lgkm ----
                f32x16 s;
                #pragma unroll
                for (int r = 0; r < 16; ++r) s[r] = 0.f;
                __builtin_amdgcn_s_setprio(1);
                s = MFMA32(k0, qb0, s);
                s = MFMA32(k1, qb1, s);
                s = MFMA32(k2, qb2, s);
                s = MFMA32(k3, qb3, s);
                __builtin_amdgcn_s_setprio(0);

                // ---- K frags for chunk kc+2: issue right after consumption ----
                if (kc + 2 < nkc) {
                    const __bf16* kf = Kfrag + (size_t)(kc + 2) * 64 * HD;
                    k0 = *(const bf16x8*)(kf);
                    k1 = *(const bf16x8*)(kf + 16);
                    k2 = *(const bf16x8*)(kf + 32);
                    k3 = *(const bf16x8*)(kf + 48);
                }

                if (kc == tile && qg == kg) {      // diagonal 32x32 mask
                    #pragma unroll
                    for (int r = 0; r < 16; ++r) {
                        const int cr = (r & 3) + 8 * (r >> 2) + 4 * hi;
                        if (cr > l32) s[r] = -1e30f;
                    }
                }

                float p[16];
                #pragma unroll
                for (int r = 0; r < 16; ++r) p[r] = fast_exp2(s[r]);
                #pragma unroll
                for (int r = 0; r < 8; ++r) { rs0 += p[2 * r]; rs1 += p[2 * r + 1]; }

                // in-register P -> PV A-frags (cvt_pk + permlane32_swap)
                unsigned int w0, w1, w2, w3, w4, w5, w6, w7;
                CVTPK(w0, p[0],  p[1]);  CVTPK(w1, p[2],  p[3]);
                CVTPK(w2, p[4],  p[5]);  CVTPK(w3, p[6],  p[7]);
                CVTPK(w4, p[8],  p[9]);  CVTPK(w5, p[10], p[11]);
                CVTPK(w6, p[12], p[13]); CVTPK(w7, p[14], p[15]);
                PLSWAP(w0, w2); PLSWAP(w1, w3); PLSWAP(w4, w6); PLSWAP(w5, w7);
                uint32x4 u0 = {w0, w1, w2, w3};
                uint32x4 u1 = {w4, w5, w6, w7};
                const bf16x8 pa0 = *(const bf16x8*)&u0;
                const bf16x8 pa1 = *(const bf16x8*)&u1;

                __builtin_amdgcn_s_setprio(1);
                #pragma unroll
                for (int et = 0; et < 2; ++et) {
                    const __bf16* vp = (const __bf16*)&VT2[buf][(et * 32 + l32) * 36]
                                       + 32 * kg + hi * 8;
                    accO[et] = MFMA32(pa0, *(const bf16x8*)(vp),      accO[et]);
                    accO[et] = MFMA32(pa1, *(const bf16x8*)(vp + 16), accO[et]);
                }
                __builtin_amdgcn_s_setprio(0);
            }
        };

        for (int kc = 0; kc < nkc; kc += 2) {
            STEP(kc, 0, kA0, kA1, kA2, kA3, vAl, vAh);
            if (kc + 1 < nkc) STEP(kc + 1, 1, kB0, kB1, kB2, kB3, vBl, vBh);
        }

        // ---- epilogue: reduce kg-pairs through (dead) VT2, normalize ----
        __syncthreads();
        float* red = (float*)VT2;
        float rsum = rs0 + rs1;
        if (kg == 1) {
            float* dst = red + (size_t)(qg * 64 + lane) * 33;
            #pragma unroll
            for (int r = 0; r < 16; ++r) { dst[r] = accO[0][r]; dst[16 + r] = accO[1][r]; }
            dst[32] = rsum;
        }
        __syncthreads();
        if (kg == 0) {
            const float* src = red + (size_t)(qg * 64 + lane) * 33;
            #pragma unroll
            for (int r = 0; r < 16; ++r) { accO[0][r] += src[r]; accO[1][r] += src[16 + r]; }
            rsum += src[32];
            const float rt  = rsum + __shfl_xor(rsum, 32, 64);
            const float ivq = 1.0f / rt;
            const int b = bh >> 4, h = bh & 15;
            #pragma unroll
            for (int r = 0; r < 16; ++r) {
                const int cr = (r & 3) + 8 * (r >> 2) + 4 * hi;
                const float iv = __shfl(ivq, cr, 64);
                __bf16* ao = AO + (size_t)(b * SEQ + q0 + 32 * qg + cr) * DM + h * HD;
                ao[l32]      = (__bf16)(accO[0][r] * iv);
                ao[32 + l32] = (__bf16)(accO[1][r] * iv);
            }
        }
    }
}

// ---------------------------------------------------------------------------
// Kernel 2.5: convert Wo to bf16 once (unchanged).
// ---------------------------------------------------------------------------
__global__ __launch_bounds__(256)
void wconv_kernel(const float* __restrict__ Wo, __bf16* __restrict__ Wb)
{
    const size_t i = ((size_t)blockIdx.x * 256 + threadIdx.x) * 8;
    *(bf16x8*)(Wb + i) = ld8_f32(Wo + i);
}

// ---------------------------------------------------------------------------
// Kernel 3: out = AO @ Wb^T + bo (round-9 verified version, unchanged):
// 64x64 tile, 4 waves = 2m x 2n, one 32x32 MFMA32 acc/wave, 1024 blocks,
// XCD-bijective swizzle, depth-2 counted-vmcnt pipeline.
// ---------------------------------------------------------------------------
__global__ __launch_bounds__(256)
void ogemm_kernel(const __bf16* __restrict__ AO, const __bf16* __restrict__ Wb,
                  const float* __restrict__ bo, float* __restrict__ out)
{
    __shared__ __align__(16) unsigned int A_lds[2][64 * 36];
    __shared__ __align__(16) unsigned int B_lds[2][64 * 36];

    const int tid  = threadIdx.x;
    const int w    = tid >> 6;
    const int lane = tid & 63;
    const int hi   = lane >> 5;
    const int l32  = lane & 31;
    const int wm   = w >> 1;            // m half (32 rows)
    const int wn   = w & 1;             // n half (32 cols)

    // XCD-bijective swizzle: xcd = L&7 owns m-tiles [xcd*8, xcd*8+8).
    const int L   = blockIdx.x;
    const int xcd = L & 7;
    const int r_  = L >> 3;                      // 0..127
    const int n0  = (r_ & 15) * 64;              // 16 n-tiles
    const int m0  = (xcd * 8 + (r_ >> 4)) * 64;  // 64 m-tiles, XCD-pinned

    const int row = tid >> 3, c = tid & 7;       // staging: 8 threads/row

    f32x16 acc;
    #pragma unroll
    for (int r = 0; r < 16; ++r) acc[r] = 0.f;

    // prologue: chunk 0 -> set A, chunk 1 -> set B (depth 2; DM/64 = 16)
    uint32x4 aA[2], bA[2], aB[2], bB[2];
    #pragma unroll
    for (int i = 0; i < 2; ++i) {
        aA[i] = *(const uint32x4*)(AO + (size_t)(m0 + row + i * 32) * DM + c * 8);
        bA[i] = *(const uint32x4*)(Wb + (size_t)(n0 + row + i * 32) * DM + c * 8);
        aB[i] = *(const uint32x4*)(AO + (size_t)(m0 + row + i * 32) * DM + 64 + c * 8);
        bB[i] = *(const uint32x4*)(Wb + (size_t)(n0 + row + i * 32) * DM + 64 + c * 8);
    }

    auto GSTEP = [&](int kc, int buf, uint32x4 (&ap)[2], uint32x4 (&bp)[2]) {
        #pragma unroll
        for (int i = 0; i < 2; ++i) {
            *(uint32x4*)&A_lds[buf][(row + i * 32) * 36 + c * 4] = ap[i];
            *(uint32x4*)&B_lds[buf][(row + i * 32) * 36 + c * 4] = bp[i];
        }

        // issue next-set loads before the barrier (progress during wait)
        if (kc + 2 < DM / 64) {
            const size_t o = (size_t)(kc + 2) * 64;
            #pragma unroll
            for (int i = 0; i < 2; ++i) {
                ap[i] = *(const uint32x4*)(AO + (size_t)(m0 + row + i * 32) * DM + o + c * 8);
                bp[i] = *(const uint32x4*)(Wb + (size_t)(n0 + row + i * 32) * DM + o + c * 8);
            }
        }
        BAR_KEEP_VMEM();   // writes visible; next set's loads stay in flight

        // A[m = wm*32 + l32][k], B[n = wn*32 + l32][k]; 4 k-slices of 16
        const __bf16* ap2 = (const __bf16*)&A_lds[buf][(wm * 32 + l32) * 36] + hi * 8;
        const __bf16* bp2 = (const __bf16*)&B_lds[buf][(wn * 32 + l32) * 36] + hi * 8;
        #pragma unroll
        for (int f = 0; f < 4; ++f)
            acc = MFMA32(*(const bf16x8*)(ap2 + 16 * f),
                         *(const bf16x8*)(bp2 + 16 * f), acc);
    };

    for (int kc = 0; kc < DM / 64; kc += 2) {
        GSTEP(kc,     0, aA, bA);
        GSTEP(kc + 1, 1, aB, bB);
    }

    // D[m = crow(r,hi)][n = l32]: coalesced 32-lane f32 runs per reg.
    const int n = n0 + wn * 32 + l32;
    const float bof = bo[n];
    #pragma unroll
    for (int r = 0; r < 16; ++r) {
        const int cr = (r & 3) + 8 * (r >> 2) + 4 * hi;
        out[(size_t)(m0 + wm * 32 + cr) * DM + n] = acc[r] + bof;
    }
}

// ---------------------------------------------------------------------------
extern "C" void kernel_launch(void* const* d_in, const int* in_sizes, int n_in,
                              void* d_out, int out_size, void* d_ws, size_t ws_size,
                              hipStream_t stream)
{
    const float* key   = (const float*)d_in[0];
    const float* query = (const float*)d_in[1];
    const float* value = (const float*)d_in[2];
    // d_in[3] = mask: always tril (causal) — implemented analytically, not read
    const float* Wq = (const float*)d_in[4];
    const float* Wk = (const float*)d_in[5];
    const float* Wv = (const float*)d_in[6];
    const float* Wo = (const float*)d_in[7];
    const float* bo = (const float*)d_in[8];

    const size_t per = (size_t)BATCH * NH * SEQ * HD;
    __bf16* Qp = (__bf16*)d_ws;
    __bf16* Kp = Qp + per;
    __bf16* Vp = Kp + per;
    __bf16* AO = Vp + per;
    __bf16* Wb = Kp;   // Kp region dead after attn; reuse for bf16 Wo

    proj_kernel<<<dim3(SEQ / 64, BATCH * NH, 3), 256, 0, stream>>>(
        query, key, value, Wq, Wk, Wv, Qp, Kp, Vp);
    attn_kernel<<<dim3(16 * BATCH * NH), 256, 0, stream>>>(Qp, Kp, Vp, AO);
    wconv_kernel<<<dim3(DM * DM / (256 * 8)), 256, 0, stream>>>(Wo, Wb);
    ogemm_kernel<<<dim3(64 * 16), 256, 0, stream>>>(
        AO, Wb, bo, (float*)d_out);
}

// Round 11
// 183.348 us; speedup vs baseline: 1.0892x; 1.0892x over previous
//
#include <hip/hip_runtime.h>

typedef __bf16 bf16x8 __attribute__((ext_vector_type(8)));
typedef float  f32x4  __attribute__((ext_vector_type(4)));
typedef float  f32x16 __attribute__((ext_vector_type(16)));
typedef unsigned int uint32x4 __attribute__((ext_vector_type(4)));

#define MFMA16(a, b, c) __builtin_amdgcn_mfma_f32_16x16x32_bf16((a), (b), (c), 0, 0, 0)
#define MFMA32(a, b, c) __builtin_amdgcn_mfma_f32_32x32x16_bf16((a), (b), (c), 0, 0, 0)

// no builtin for cvt_pk on gfx950 (learn_hip m240) -> inline asm
#define CVTPK(d, x, y) asm("v_cvt_pk_bf16_f32 %0, %1, %2" : "=v"(d) : "v"(x), "v"(y))
// v_permlane32_swap: dst.hi <-> src.lo (CDNA4). Both outputs used.
#define PLSWAP(a, b)   asm("v_permlane32_swap_b32 %0, %1" : "+v"(a), "+v"(b))

// raw barrier: drain own ds ops (lgkm) for cross-wave visibility, but keep
// global prefetch loads IN FLIGHT across the barrier (no vmcnt drain).
#define BAR_KEEP_VMEM() asm volatile("s_waitcnt lgkmcnt(0)\n\ts_barrier" ::: "memory")

__device__ inline float fast_exp2(float x) {
#if __has_builtin(__builtin_amdgcn_exp2f)
    return __builtin_amdgcn_exp2f(x);   // single v_exp_f32
#else
    return exp2f(x);
#endif
}

constexpr int SEQ = 2048;
constexpr int DM  = 1024;
constexpr int NH  = 16;
constexpr int HD  = 64;
constexpr int BATCH = 2;

// load 8 consecutive f32, convert to bf16x8 (RNE)
__device__ inline bf16x8 ld8_f32(const float* p) {
    f32x4 a = *(const f32x4*)p;
    f32x4 b = *(const f32x4*)(p + 4);
    bf16x8 r;
    r[0] = (__bf16)a[0]; r[1] = (__bf16)a[1]; r[2] = (__bf16)a[2]; r[3] = (__bf16)a[3];
    r[4] = (__bf16)b[0]; r[5] = (__bf16)b[1]; r[6] = (__bf16)b[2]; r[7] = (__bf16)b[3];
    return r;
}

// ---------------------------------------------------------------------------
// Kernel 1: per-head projections (unchanged). Q pre-scaled by 1/8*log2(e).
// ---------------------------------------------------------------------------
__global__ __launch_bounds__(256)
void proj_kernel(const float* __restrict__ Xq, const float* __restrict__ Xk,
                 const float* __restrict__ Xv,
                 const float* __restrict__ Wq, const float* __restrict__ Wk,
                 const float* __restrict__ Wv,
                 __bf16* __restrict__ Qp, __bf16* __restrict__ Kp,
                 __bf16* __restrict__ Vp)
{
    const int tid  = threadIdx.x;
    const int w    = tid >> 6;
    const int lane = tid & 63;
    const int quad = lane >> 4;
    const int l16  = lane & 15;
    const int sblk = blockIdx.x;
    const int bh   = blockIdx.y;
    const int tz   = blockIdx.z;

    const float* X = (tz == 0) ? Xq : (tz == 1) ? Xk : Xv;
    const float* W = (tz == 0) ? Wq : (tz == 1) ? Wk : Wv;
    __bf16*      O = (tz == 0) ? Qp : (tz == 1) ? Kp : Vp;
    const float scale = (tz == 0) ? (0.125f * 1.44269504088896f) : 1.0f;

    const int b = bh >> 4, h = bh & 15;
    const int mrow = sblk * 64 + w * 16 + l16;

    const size_t xoff = (size_t)(b * SEQ + mrow) * DM + h * HD + quad * 8;
    bf16x8 a0 = ld8_f32(X + xoff);
    bf16x8 a1 = ld8_f32(X + xoff + 32);

    f32x4 acc[4];
    #pragma unroll
    for (int nt = 0; nt < 4; ++nt) {
        const size_t woff = (size_t)(nt * 16 + l16) * HD + quad * 8;
        bf16x8 b0 = ld8_f32(W + woff);
        bf16x8 b1 = ld8_f32(W + woff + 32);
        f32x4 c = {0.f, 0.f, 0.f, 0.f};
        c = MFMA16(a0, b0, c);
        c = MFMA16(a1, b1, c);
        acc[nt] = c;
    }

    __bf16* obase = O + (size_t)bh * SEQ * HD;
    #pragma unroll
    for (int nt = 0; nt < 4; ++nt) {
        #pragma unroll
        for (int r = 0; r < 4; ++r) {
            const int srow = sblk * 64 + w * 16 + quad * 4 + r;
            obase[(size_t)srow * HD + nt * 16 + l16] = (__bf16)(acc[nt][r] * scale);
        }
    }
}

// ---------------------------------------------------------------------------
// Kernel 2: causal flash attention (round-8/9 verified text: paired 512-block
// grid, XCD-pinned bh, chunk-64, K+V LDS staging (K staging = coalescer —
// round-10 proved removing it regresses 34%), depth-2 prefetch,
// counted-vmcnt raw barrier, setprio around MFMA clusters).
// ---------------------------------------------------------------------------
__global__ __launch_bounds__(256, 2)
void attn_kernel(const __bf16* __restrict__ Qp, const __bf16* __restrict__ Kp,
                 const __bf16* __restrict__ Vp, __bf16* __restrict__ AO)
{
    __shared__ __align__(16) unsigned int K_lds[2][64 * 36];  // + epilogue scratch
    __shared__ __align__(16) unsigned int VT2[2][64 * 36];    // V^T packed

    const int tid  = threadIdx.x;
    const int w    = tid >> 6;
    const int lane = tid & 63;
    const int hi   = lane >> 5;
    const int l32  = lane & 31;
    const int qg   = w >> 1;        // q sub-tile (32 rows)
    const int kg   = w & 1;         // k half of the 64-chunk

    // XCD swizzle (round 3): xcd = L%8, pr fastest within xcd, bh pinned.
    const int L   = blockIdx.x;
    const int pr  = (L >> 3) & 15;              // pair index 0..15
    const int bh  = (L & 7) + 8 * (L >> 7);     // 0..31

    const __bf16* Qb = Qp + (size_t)bh * SEQ * HD;
    const __bf16* Kb = Kp + (size_t)bh * SEQ * HD;
    const __bf16* Vb = Vp + (size_t)bh * SEQ * HD;

    const int krow = tid >> 3, kcol = tid & 7;
    const int jp = tid & 31, d0 = (tid >> 5) * 8;

    #pragma unroll
    for (int phase = 0; phase < 2; ++phase) {
        const int tile = (phase == 0) ? (31 - pr) : pr;  // heavy first
        const int q0   = tile * 64;
        const int nkc  = tile + 1;

        __syncthreads();  // phase boundary: epilogue scratch reads done

        // Q B-frags in registers: B[n=q=l32][k = i*16 + hi*8 + j]
        const __bf16* qp = Qb + (size_t)(q0 + 32 * qg + l32) * HD + hi * 8;
        const bf16x8 qb0 = *(const bf16x8*)(qp);
        const bf16x8 qb1 = *(const bf16x8*)(qp + 16);
        const bf16x8 qb2 = *(const bf16x8*)(qp + 32);
        const bf16x8 qb3 = *(const bf16x8*)(qp + 48);

        f32x16 accO[2];
        #pragma unroll
        for (int et = 0; et < 2; ++et) {
            #pragma unroll
            for (int r = 0; r < 16; ++r) accO[et][r] = 0.f;
        }
        float rs0 = 0.f, rs1 = 0.f;

        // prologue: chunk 0 -> set A, chunk 1 -> set B (depth 2)
        uint32x4 kA0, kA1, vAl, vAh, kB0, kB1, vBl, vBh;
        kA0 = *(const uint32x4*)(Kb + (size_t)krow * HD + kcol * 8);
        kA1 = *(const uint32x4*)(Kb + (size_t)(krow + 32) * HD + kcol * 8);
        vAl = *(const uint32x4*)(Vb + (size_t)(2 * jp) * HD + d0);
        vAh = *(const uint32x4*)(Vb + (size_t)(2 * jp + 1) * HD + d0);
        if (nkc > 1) {
            kB0 = *(const uint32x4*)(Kb + (size_t)(64 + krow) * HD + kcol * 8);
            kB1 = *(const uint32x4*)(Kb + (size_t)(64 + krow + 32) * HD + kcol * 8);
            vBl = *(const uint32x4*)(Vb + (size_t)(64 + 2 * jp) * HD + d0);
            vBh = *(const uint32x4*)(Vb + (size_t)(64 + 2 * jp + 1) * HD + d0);
        }

        auto STEP = [&](int kc, int buf, uint32x4& kp0, uint32x4& kp1,
                        uint32x4& vl, uint32x4& vh) {
            // ---- stage reg set into LDS buf ----
            *(uint32x4*)&K_lds[buf][krow * 36 + kcol * 4]        = kp0;
            *(uint32x4*)&K_lds[buf][(krow + 32) * 36 + kcol * 4] = kp1;
            #pragma unroll
            for (int i2 = 0; i2 < 4; ++i2) {
                const unsigned int va = vl[i2], vb = vh[i2];
                VT2[buf][(d0 + 2 * i2    ) * 36 + jp] = (va & 0xffffu) | (vb << 16);
                VT2[buf][(d0 + 2 * i2 + 1) * 36 + jp] = (va >> 16) | (vb & 0xffff0000u);
            }

            // ---- issue loads for chunk kc+2 BEFORE the barrier ----
            if (kc + 2 < nkc) {
                const size_t o = (size_t)(kc + 2) * 64;
                kp0 = *(const uint32x4*)(Kb + (o + krow) * HD + kcol * 8);
                kp1 = *(const uint32x4*)(Kb + (o + krow + 32) * HD + kcol * 8);
                vl  = *(const uint32x4*)(Vb + (o + 2 * jp) * HD + d0);
                vh  = *(const uint32x4*)(Vb + (o + 2 * jp + 1) * HD + d0);
            }
            BAR_KEEP_VMEM();   // writes visible; prefetch loads stay in flight

            // wave (qg=0,kg=1) at diagonal chunk: fully masked -> skip compute
            if (!(kc == tile && qg == 0 && kg == 1)) {
                // ---- S^T = K.Q^T : D[row=k(crow), col=q(l32)], exp2 domain ----
                const __bf16* kp = (const __bf16*)&K_lds[buf][(32 * kg + l32) * 36] + hi * 8;
                f32x16 s;
                #pragma unroll
                for (int r = 0; r < 16; ++r) s[r] = 0.f;
                __builtin_amdgcn_s_setprio(1);
                s = MFMA32(*(const bf16x8*)(kp),      qb0, s);
                s = MFMA32(*(const bf16x8*)(kp + 16), qb1, s);
                s = MFMA32(*(const bf16x8*)(kp + 32), qb2, s);
                s = MFMA32(*(const bf16x8*)(kp + 48), qb3, s);
                __builtin_amdgcn_s_setprio(0);

                if (kc == tile && qg == kg) {      // diagonal 32x32 mask
                    #pragma unroll
                    for (int r = 0; r < 16; ++r) {
                        const int cr = (r & 3) + 8 * (r >> 2) + 4 * hi;
                        if (cr > l32) s[r] = -1e30f;
                    }
                }

                float p[16];
                #pragma unroll
                for (int r = 0; r < 16; ++r) p[r] = fast_exp2(s[r]);
                #pragma unroll
                for (int r = 0; r < 8; ++r) { rs0 += p[2 * r]; rs1 += p[2 * r + 1]; }

                // in-register P -> PV A-frags (cvt_pk + permlane32_swap)
                unsigned int w0, w1, w2, w3, w4, w5, w6, w7;
                CVTPK(w0, p[0],  p[1]);  CVTPK(w1, p[2],  p[3]);
                CVTPK(w2, p[4],  p[5]);  CVTPK(w3, p[6],  p[7]);
                CVTPK(w4, p[8],  p[9]);  CVTPK(w5, p[10], p[11]);
                CVTPK(w6, p[12], p[13]); CVTPK(w7, p[14], p[15]);
                PLSWAP(w0, w2); PLSWAP(w1, w3); PLSWAP(w4, w6); PLSWAP(w5, w7);
                uint32x4 u0 = {w0, w1, w2, w3};
                uint32x4 u1 = {w4, w5, w6, w7};
                const bf16x8 pa0 = *(const bf16x8*)&u0;
                const bf16x8 pa1 = *(const bf16x8*)&u1;

                __builtin_amdgcn_s_setprio(1);
                #pragma unroll
                for (int et = 0; et < 2; ++et) {
                    const __bf16* vp = (const __bf16*)&VT2[buf][(et * 32 + l32) * 36]
                                       + 32 * kg + hi * 8;
                    accO[et] = MFMA32(pa0, *(const bf16x8*)(vp),      accO[et]);
                    accO[et] = MFMA32(pa1, *(const bf16x8*)(vp + 16), accO[et]);
                }
                __builtin_amdgcn_s_setprio(0);
            }
        };

        for (int kc = 0; kc < nkc; kc += 2) {
            STEP(kc, 0, kA0, kA1, vAl, vAh);
            if (kc + 1 < nkc) STEP(kc + 1, 1, kB0, kB1, vBl, vBh);
        }

        // ---- epilogue: reduce kg-pairs through (dead) K_lds, normalize ----
        __syncthreads();
        float* red = (float*)K_lds;
        float rsum = rs0 + rs1;
        if (kg == 1) {
            float* dst = red + (size_t)(qg * 64 + lane) * 33;
            #pragma unroll
            for (int r = 0; r < 16; ++r) { dst[r] = accO[0][r]; dst[16 + r] = accO[1][r]; }
            dst[32] = rsum;
        }
        __syncthreads();
        if (kg == 0) {
            const float* src = red + (size_t)(qg * 64 + lane) * 33;
            #pragma unroll
            for (int r = 0; r < 16; ++r) { accO[0][r] += src[r]; accO[1][r] += src[16 + r]; }
            rsum += src[32];
            const float rt  = rsum + __shfl_xor(rsum, 32, 64);
            const float ivq = 1.0f / rt;
            const int b = bh >> 4, h = bh & 15;
            #pragma unroll
            for (int r = 0; r < 16; ++r) {
                const int cr = (r & 3) + 8 * (r >> 2) + 4 * hi;
                const float iv = __shfl(ivq, cr, 64);
                __bf16* ao = AO + (size_t)(b * SEQ + q0 + 32 * qg + cr) * DM + h * HD;
                ao[l32]      = (__bf16)(accO[0][r] * iv);
                ao[32 + l32] = (__bf16)(accO[1][r] * iv);
            }
        }
    }
}

// ---------------------------------------------------------------------------
// Kernel 2.5: convert Wo to bf16 once (unchanged).
// ---------------------------------------------------------------------------
__global__ __launch_bounds__(256)
void wconv_kernel(const float* __restrict__ Wo, __bf16* __restrict__ Wb)
{
    const size_t i = ((size_t)blockIdx.x * 256 + threadIdx.x) * 8;
    *(bf16x8*)(Wb + i) = ld8_f32(Wo + i);
}

// ---------------------------------------------------------------------------
// Kernel 3: out = AO @ Wb^T + bo (round-9 verified version, unchanged):
// 64x64 tile, 4 waves = 2m x 2n, one 32x32 MFMA32 acc/wave, 1024 blocks,
// XCD-bijective swizzle, depth-2 counted-vmcnt pipeline.
// ---------------------------------------------------------------------------
__global__ __launch_bounds__(256)
void ogemm_kernel(const __bf16* __restrict__ AO, const __bf16* __restrict__ Wb,
                  const float* __restrict__ bo, float* __restrict__ out)
{
    __shared__ __align__(16) unsigned int A_lds[2][64 * 36];
    __shared__ __align__(16) unsigned int B_lds[2][64 * 36];

    const int tid  = threadIdx.x;
    const int w    = tid >> 6;
    const int lane = tid & 63;
    const int hi   = lane >> 5;
    const int l32  = lane & 31;
    const int wm   = w >> 1;            // m half (32 rows)
    const int wn   = w & 1;             // n half (32 cols)

    // XCD-bijective swizzle: xcd = L&7 owns m-tiles [xcd*8, xcd*8+8).
    const int L   = blockIdx.x;
    const int xcd = L & 7;
    const int r_  = L >> 3;                      // 0..127
    const int n0  = (r_ & 15) * 64;              // 16 n-tiles
    const int m0  = (xcd * 8 + (r_ >> 4)) * 64;  // 64 m-tiles, XCD-pinned

    const int row = tid >> 3, c = tid & 7;       // staging: 8 threads/row

    f32x16 acc;
    #pragma unroll
    for (int r = 0; r < 16; ++r) acc[r] = 0.f;

    // prologue: chunk 0 -> set A, chunk 1 -> set B (depth 2; DM/64 = 16)
    uint32x4 aA[2], bA[2], aB[2], bB[2];
    #pragma unroll
    for (int i = 0; i < 2; ++i) {
        aA[i] = *(const uint32x4*)(AO + (size_t)(m0 + row + i * 32) * DM + c * 8);
        bA[i] = *(const uint32x4*)(Wb + (size_t)(n0 + row + i * 32) * DM + c * 8);
        aB[i] = *(const uint32x4*)(AO + (size_t)(m0 + row + i * 32) * DM + 64 + c * 8);
        bB[i] = *(const uint32x4*)(Wb + (size_t)(n0 + row + i * 32) * DM + 64 + c * 8);
    }

    auto GSTEP = [&](int kc, int buf, uint32x4 (&ap)[2], uint32x4 (&bp)[2]) {
        #pragma unroll
        for (int i = 0; i < 2; ++i) {
            *(uint32x4*)&A_lds[buf][(row + i * 32) * 36 + c * 4] = ap[i];
            *(uint32x4*)&B_lds[buf][(row + i * 32) * 36 + c * 4] = bp[i];
        }

        // issue next-set loads before the barrier (progress during wait)
        if (kc + 2 < DM / 64) {
            const size_t o = (size_t)(kc + 2) * 64;
            #pragma unroll
            for (int i = 0; i < 2; ++i) {
                ap[i] = *(const uint32x4*)(AO + (size_t)(m0 + row + i * 32) * DM + o + c * 8);
                bp[i] = *(const uint32x4*)(Wb + (size_t)(n0 + row + i * 32) * DM + o + c * 8);
            }
        }
        BAR_KEEP_VMEM();   // writes visible; next set's loads stay in flight

        // A[m = wm*32 + l32][k], B[n = wn*32 + l32][k]; 4 k-slices of 16
        const __bf16* ap2 = (const __bf16*)&A_lds[buf][(wm * 32 + l32) * 36] + hi * 8;
        const __bf16* bp2 = (const __bf16*)&B_lds[buf][(wn * 32 + l32) * 36] + hi * 8;
        #pragma unroll
        for (int f = 0; f < 4; ++f)
            acc = MFMA32(*(const bf16x8*)(ap2 + 16 * f),
                         *(const bf16x8*)(bp2 + 16 * f), acc);
    };

    for (int kc = 0; kc < DM / 64; kc += 2) {
        GSTEP(kc,     0, aA, bA);
        GSTEP(kc + 1, 1, aB, bB);
    }

    // D[m = crow(r,hi)][n = l32]: coalesced 32-lane f32 runs per reg.
    const int n = n0 + wn * 32 + l32;
    const float bof = bo[n];
    #pragma unroll
    for (int r = 0; r < 16; ++r) {
        const int cr = (r & 3) + 8 * (r >> 2) + 4 * hi;
        out[(size_t)(m0 + wm * 32 + cr) * DM + n] = acc[r] + bof;
    }
}

// ---------------------------------------------------------------------------
extern "C" void kernel_launch(void* const* d_in, const int* in_sizes, int n_in,
                              void* d_out, int out_size, void* d_ws, size_t ws_size,
                              hipStream_t stream)
{
    const float* key   = (const float*)d_in[0];
    const float* query = (const float*)d_in[1];
    const float* value = (const float*)d_in[2];
    // d_in[3] = mask: always tril (causal) — implemented analytically, not read
    const float* Wq = (const float*)d_in[4];
    const float* Wk = (const float*)d_in[5];
    const float* Wv = (const float*)d_in[6];
    const float* Wo = (const float*)d_in[7];
    const float* bo = (const float*)d_in[8];

    const size_t per = (size_t)BATCH * NH * SEQ * HD;
    __bf16* Qp = (__bf16*)d_ws;
    __bf16* Kp = Qp + per;
    __bf16* Vp = Kp + per;
    __bf16* AO = Vp + per;
    __bf16* Wb = Kp;   // Kp region dead after attn; reuse for bf16 Wo

    proj_kernel<<<dim3(SEQ / 64, BATCH * NH, 3), 256, 0, stream>>>(
        query, key, value, Wq, Wk, Wv, Qp, Kp, Vp);
    attn_kernel<<<dim3(16 * BATCH * NH), 256, 0, stream>>>(Qp, Kp, Vp, AO);
    wconv_kernel<<<dim3(DM * DM / (256 * 8)), 256, 0, stream>>>(Wo, Wb);
    ogemm_kernel<<<dim3(64 * 16), 256, 0, stream>>>(
        AO, Wb, bo, (float*)d_out);
}